// Round 10
// baseline (161.553 us; speedup 1.0000x reference)
//
#include <hip/hip_runtime.h>

// Problem constants (from reference setup_inputs)
constexpr int B_  = 8;
constexpr int T_  = 16;
constexpr int C_  = 256;
constexpr int HW_ = 784;   // 28*28
constexpr int CO_ = 64;    // C/4
constexpr int K_  = 7;     // KSZ
constexpr int U2_ = 32;    // 2*T
constexpr int REPS = 4;    // instrumentation: internal idempotent repeats

typedef float floatx4 __attribute__((ext_vector_type(4)));

__device__ __forceinline__ float rfl(float v) {
    return __int_as_float(__builtin_amdgcn_readfirstlane(__float_as_int(v)));
}

// ---------------------------------------------------------------------------
// Kernel 1 (instrumented x4): pooled[b,c,t] = mean_hw x[b,t,c,:,:]
// ---------------------------------------------------------------------------
__global__ __launch_bounds__(256) void pool_kernel4(const float* __restrict__ x,
                                                    float* __restrict__ pooled) {
    int bid  = blockIdx.x;
    int cg   = bid & 63;
    int bt   = bid >> 6;
    int t    = bt & 15;
    int b    = bt >> 4;
    int wave = threadIdx.x >> 6;
    int lane = threadIdx.x & 63;
    int c    = cg * 4 + wave;

    const floatx4* p4 = (const floatx4*)(x + ((size_t)bt * C_ + c) * HW_);
    size_t oidx = ((size_t)b * C_ + c) * T_ + t;

    for (int rep = 0; rep < REPS; ++rep) {
        float s = 0.f;
        for (int j = lane; j < 196; j += 64) {
            floatx4 v = p4[j];
            s += (v.x + v.y) + (v.z + v.w);
        }
#pragma unroll
        for (int m = 32; m >= 1; m >>= 1) s += __shfl_xor(s, m, 64);
        if (lane == 0) pooled[oidx] = s * (1.0f / 784.0f);
        asm volatile("" ::: "memory");   // force reloads next rep
    }
}

// ---------------------------------------------------------------------------
// Kernel 2: L-branch conv1d (C -> C/4, k=7, pad=3) + tanh  (not instrumented)
// ---------------------------------------------------------------------------
__global__ __launch_bounds__(256) void ty_kernel(const float* __restrict__ pooled,
                                                 const float* __restrict__ Wl1,
                                                 float* __restrict__ ty) {
    int b = blockIdx.x / CO_;
    int o = blockIdx.x % CO_;
    __shared__ float pld[T_ * 257];

    int tid = threadIdx.x;
    for (int idx = tid; idx < C_ * T_; idx += 256) {
        int i  = idx >> 4;
        int tt = idx & 15;
        pld[tt * 257 + i] = pooled[((size_t)b * C_ + i) * T_ + tt];
    }
    __syncthreads();

    int t = tid >> 4;
    int q = tid & 15;
    const float* wrow = Wl1 + (size_t)o * (C_ * K_);
    float acc = 0.f;
    for (int j = 0; j < 16; ++j) {
        int i = j * 16 + q;
        const float* wp = wrow + i * K_;
#pragma unroll
        for (int k = 0; k < K_; ++k) {
            int tt = t + k - 3;
            if (tt >= 0 && tt < T_) acc += wp[k] * pld[tt * 257 + i];
        }
    }
    acc += __shfl_xor(acc, 1, 64);
    acc += __shfl_xor(acc, 2, 64);
    acc += __shfl_xor(acc, 4, 64);
    acc += __shfl_xor(acc, 8, 64);
    if (q == 0) ty[((size_t)b * CO_ + o) * T_ + t] = tanhf(acc);
}

// ---------------------------------------------------------------------------
// Kernel 3 (instrumented x4): coefficients + stream, R6 structure.
// ---------------------------------------------------------------------------
__global__ __launch_bounds__(256) void stream_coef_kernel4(const float* __restrict__ x,
                                                           const float* __restrict__ pooled,
                                                           const float* __restrict__ ty,
                                                           const float* __restrict__ W1,
                                                           const float* __restrict__ W2,
                                                           const float* __restrict__ Wl2,
                                                           float* __restrict__ out) {
    int bc = blockIdx.x;
    int b  = bc >> 8;
    int c  = bc & 255;
    int tid = threadIdx.x;
    bool active = tid < 196;

    const size_t chan = ((size_t)(b * T_) * C_ + c) * HW_ + (size_t)tid * 4;
    const float* xb = x + chan;
    float*       ob = out + chan;
    const size_t ts = (size_t)C_ * HW_;

    __shared__ float loc_s[T_];
    __shared__ float g_s[U2_];
    __shared__ float s_s[8];
    __shared__ float kw_s[8];

    for (int rep = 0; rep < REPS; ++rep) {
        // ---- Phase A: prefetch first 11 x tiles
        floatx4 w[11];
        if (active) {
#pragma unroll
            for (int tp = 0; tp < 11; ++tp)
                w[tp] = *(const floatx4*)(xb + (size_t)tp * ts);
        }

        __syncthreads();   // protect LDS reuse across reps

        // ---- Phase B: coefficients
        {
            int t = tid >> 4, q = tid & 15;
            float acc = 0.f;
#pragma unroll
            for (int jj = 0; jj < 4; ++jj) {
                int o = q + jj * 16;
                acc += Wl2[(size_t)c * CO_ + o] * ty[((size_t)b * CO_ + o) * T_ + t];
            }
            acc += __shfl_xor(acc, 1, 64);
            acc += __shfl_xor(acc, 2, 64);
            acc += __shfl_xor(acc, 4, 64);
            acc += __shfl_xor(acc, 8, 64);
            if (q == 0) loc_s[t] = 1.0f / (1.0f + __expf(-acc));
        }
        if (tid < U2_) {
            float acc = 0.f;
#pragma unroll
            for (int t2 = 0; t2 < T_; ++t2)
                acc += pooled[(size_t)bc * T_ + t2] * W1[tid * T_ + t2];
            g_s[tid] = tanhf(acc);
        }
        __syncthreads();
        if (tid < K_) {
            float acc = 0.f;
#pragma unroll
            for (int u = 0; u < U2_; ++u) acc += g_s[u] * W2[tid * U2_ + u];
            s_s[tid] = acc;
        }
        __syncthreads();
        if (tid == 0) {
            float m = s_s[0];
#pragma unroll
            for (int k = 1; k < K_; ++k) m = fmaxf(m, s_s[k]);
            float e[K_], sum = 0.f;
#pragma unroll
            for (int k = 0; k < K_; ++k) { e[k] = __expf(s_s[k] - m); sum += e[k]; }
            float inv = 1.0f / sum;
#pragma unroll
            for (int k = 0; k < K_; ++k) kw_s[k] = e[k] * inv;
        }
        __syncthreads();

        float kw[K_], lc[T_];
#pragma unroll
        for (int k = 0; k < K_; ++k) kw[k] = rfl(kw_s[k]);
#pragma unroll
        for (int t = 0; t < T_; ++t) lc[t] = rfl(loc_s[t]);

        // ---- Phase C: gate, conv, store
        if (active) {
#pragma unroll
            for (int tp = 0; tp < 11; ++tp) w[tp] *= lc[tp];

#pragma unroll
            for (int t = 0; t < 8; ++t) {
                floatx4 acc = {0.f, 0.f, 0.f, 0.f};
#pragma unroll
                for (int d = -3; d <= 3; ++d) {
                    int tp = t + d;
                    if (tp >= 0 && tp <= 10) acc += kw[d + 3] * w[tp];
                }
                __builtin_nontemporal_store(acc, (floatx4*)(ob + (size_t)t * ts));
            }

#pragma unroll
            for (int j = 0; j < 6; ++j) w[j] = w[5 + j];
#pragma unroll
            for (int tp = 11; tp < 16; ++tp)
                w[tp - 5] = *(const floatx4*)(xb + (size_t)tp * ts) * lc[tp];

#pragma unroll
            for (int t = 8; t < 16; ++t) {
                floatx4 acc = {0.f, 0.f, 0.f, 0.f};
#pragma unroll
                for (int d = -3; d <= 3; ++d) {
                    int tp = t + d;
                    if (tp <= 15) acc += kw[d + 3] * w[tp - 5];
                }
                __builtin_nontemporal_store(acc, (floatx4*)(ob + (size_t)t * ts));
            }
        }
        asm volatile("" ::: "memory");   // force reloads next rep
    }
}

extern "C" void kernel_launch(void* const* d_in, const int* in_sizes, int n_in,
                              void* d_out, int out_size, void* d_ws, size_t ws_size,
                              hipStream_t stream) {
    const float* x   = (const float*)d_in[0];
    const float* W1  = (const float*)d_in[1];
    const float* W2  = (const float*)d_in[2];
    const float* Wl1 = (const float*)d_in[3];
    const float* Wl2 = (const float*)d_in[4];
    float* out = (float*)d_out;

    float* pooled = (float*)d_ws;              // B*C*T   = 32768 floats
    float* ty     = pooled + B_ * C_ * T_;     // B*CO*T  =  8192 floats

    pool_kernel4<<<B_ * T_ * (C_ / 4), 256, 0, stream>>>(x, pooled);
    ty_kernel<<<B_ * CO_, 256, 0, stream>>>(pooled, Wl1, ty);
    stream_coef_kernel4<<<B_ * C_, 256, 0, stream>>>(x, pooled, ty, W1, W2, Wl2, out);
}

// Round 11
// 66.983 us; speedup vs baseline: 2.4119x; 2.4119x over previous
//
#include <hip/hip_runtime.h>

// Problem constants (from reference setup_inputs)
constexpr int B_  = 8;
constexpr int T_  = 16;
constexpr int C_  = 256;
constexpr int HW_ = 784;   // 28*28
constexpr int CO_ = 64;    // C/4
constexpr int K_  = 7;     // KSZ
constexpr int U2_ = 32;    // 2*T

typedef float floatx4 __attribute__((ext_vector_type(4)));

__device__ __forceinline__ float rfl(float v) {
    return __int_as_float(__builtin_amdgcn_readfirstlane(__float_as_int(v)));
}

// ---------------------------------------------------------------------------
// Kernel 1: pool, ILP version. Block = (b, t, 64-channel group).
// 4 lanes per channel; each lane reads 49 float4s of its channel (sequential,
// 64B-line-aligned quads), reduces over the 4 lanes with 2 shuffles.
// 512 blocks x 256 threads; 49 independent loads per thread.
// ---------------------------------------------------------------------------
__global__ __launch_bounds__(256) void pool_kernel(const float* __restrict__ x,
                                                   float* __restrict__ pooled) {
    int bid = blockIdx.x;           // (b*T + t)*4 + cg
    int cg  = bid & 3;
    int bt  = bid >> 2;             // b*T + t
    int t   = bt & 15;
    int b   = bt >> 4;
    int tid = threadIdx.x;
    int c   = cg * 64 + (tid >> 2); // channel
    int j4  = tid & 3;              // sub-lane within channel

    const floatx4* p4 = (const floatx4*)(x + ((size_t)bt * C_ + c) * HW_);
    float s = 0.f;
#pragma unroll
    for (int jj = 0; jj < 49; ++jj) {
        floatx4 v = p4[j4 + 4 * jj];
        s += (v.x + v.y) + (v.z + v.w);
    }
    s += __shfl_xor(s, 1, 64);
    s += __shfl_xor(s, 2, 64);
    if (j4 == 0) pooled[((size_t)b * C_ + c) * T_ + t] = s * (1.0f / 784.0f);
}

// ---------------------------------------------------------------------------
// Kernel 2: L-branch conv1d (C -> C/4, k=7, pad=3) + tanh
// ---------------------------------------------------------------------------
__global__ __launch_bounds__(256) void ty_kernel(const float* __restrict__ pooled,
                                                 const float* __restrict__ Wl1,
                                                 float* __restrict__ ty) {
    int b = blockIdx.x / CO_;
    int o = blockIdx.x % CO_;
    __shared__ float pld[T_ * 257];   // pld[t*257 + i], padded pitch

    int tid = threadIdx.x;
    for (int idx = tid; idx < C_ * T_; idx += 256) {
        int i  = idx >> 4;
        int tt = idx & 15;
        pld[tt * 257 + i] = pooled[((size_t)b * C_ + i) * T_ + tt];
    }
    __syncthreads();

    int t = tid >> 4;   // 0..15
    int q = tid & 15;   // i-split
    const float* wrow = Wl1 + (size_t)o * (C_ * K_);
    float acc = 0.f;
    for (int j = 0; j < 16; ++j) {
        int i = j * 16 + q;
        const float* wp = wrow + i * K_;
#pragma unroll
        for (int k = 0; k < K_; ++k) {
            int tt = t + k - 3;
            if (tt >= 0 && tt < T_) acc += wp[k] * pld[tt * 257 + i];
        }
    }
    acc += __shfl_xor(acc, 1, 64);
    acc += __shfl_xor(acc, 2, 64);
    acc += __shfl_xor(acc, 4, 64);
    acc += __shfl_xor(acc, 8, 64);
    if (q == 0) ty[((size_t)b * CO_ + o) * T_ + t] = tanhf(acc);
}

// ---------------------------------------------------------------------------
// Kernel 3: fused coefficients + stream (R6 structure, best so far).
// Change vs R6: plain stores instead of nontemporal (write-path A/B).
// ---------------------------------------------------------------------------
__global__ __launch_bounds__(256) void stream_coef_kernel(const float* __restrict__ x,
                                                          const float* __restrict__ pooled,
                                                          const float* __restrict__ ty,
                                                          const float* __restrict__ W1,
                                                          const float* __restrict__ W2,
                                                          const float* __restrict__ Wl2,
                                                          float* __restrict__ out) {
    int bc = blockIdx.x;         // block-uniform
    int b  = bc >> 8;
    int c  = bc & 255;
    int tid = threadIdx.x;
    bool active = tid < 196;

    const size_t chan = ((size_t)(b * T_) * C_ + c) * HW_ + (size_t)tid * 4;
    const float* xb = x + chan;
    float*       ob = out + chan;
    const size_t ts = (size_t)C_ * HW_;   // t-stride in floats

    // ---- Phase A: prefetch first 11 x tiles (raw, loc applied later)
    floatx4 w[11];
    if (active) {
#pragma unroll
        for (int tp = 0; tp < 11; ++tp)
            w[tp] = *(const floatx4*)(xb + (size_t)tp * ts);
    }

    // ---- Phase B: coefficients (all 256 threads; loads overlap Phase A)
    __shared__ float loc_s[T_];
    __shared__ float g_s[U2_];
    __shared__ float s_s[8];
    __shared__ float kw_s[8];

    {   // loc: 16 t-groups x 16 o-splitters (4 o each)
        int t = tid >> 4, q = tid & 15;
        float acc = 0.f;
#pragma unroll
        for (int jj = 0; jj < 4; ++jj) {
            int o = q + jj * 16;
            acc += Wl2[(size_t)c * CO_ + o] * ty[((size_t)b * CO_ + o) * T_ + t];
        }
        acc += __shfl_xor(acc, 1, 64);
        acc += __shfl_xor(acc, 2, 64);
        acc += __shfl_xor(acc, 4, 64);
        acc += __shfl_xor(acc, 8, 64);
        if (q == 0) loc_s[t] = 1.0f / (1.0f + __expf(-acc));
    }
    if (tid < U2_) {
        float acc = 0.f;
#pragma unroll
        for (int t2 = 0; t2 < T_; ++t2)
            acc += pooled[(size_t)bc * T_ + t2] * W1[tid * T_ + t2];
        g_s[tid] = tanhf(acc);
    }
    __syncthreads();
    if (tid < K_) {
        float acc = 0.f;
#pragma unroll
        for (int u = 0; u < U2_; ++u) acc += g_s[u] * W2[tid * U2_ + u];
        s_s[tid] = acc;
    }
    __syncthreads();
    if (tid == 0) {
        float m = s_s[0];
#pragma unroll
        for (int k = 1; k < K_; ++k) m = fmaxf(m, s_s[k]);
        float e[K_], sum = 0.f;
#pragma unroll
        for (int k = 0; k < K_; ++k) { e[k] = __expf(s_s[k] - m); sum += e[k]; }
        float inv = 1.0f / sum;
#pragma unroll
        for (int k = 0; k < K_; ++k) kw_s[k] = e[k] * inv;
    }
    __syncthreads();

    // uniform coefficients -> SGPR
    float kw[K_], lc[T_];
#pragma unroll
    for (int k = 0; k < K_; ++k) kw[k] = rfl(kw_s[k]);
#pragma unroll
    for (int t = 0; t < T_; ++t) lc[t] = rfl(loc_s[t]);

    if (!active) return;

    // ---- Phase C: gate, conv, store
#pragma unroll
    for (int tp = 0; tp < 11; ++tp) w[tp] *= lc[tp];

#pragma unroll
    for (int t = 0; t < 8; ++t) {
        floatx4 acc = {0.f, 0.f, 0.f, 0.f};
#pragma unroll
        for (int d = -3; d <= 3; ++d) {
            int tp = t + d;
            if (tp >= 0 && tp <= 10) acc += kw[d + 3] * w[tp];
        }
        *(floatx4*)(ob + (size_t)t * ts) = acc;
    }

    // shift window: w[0..5] = y[5..10]; load y[11..15] into w[6..10]
#pragma unroll
    for (int j = 0; j < 6; ++j) w[j] = w[5 + j];
#pragma unroll
    for (int tp = 11; tp < 16; ++tp)
        w[tp - 5] = *(const floatx4*)(xb + (size_t)tp * ts) * lc[tp];

#pragma unroll
    for (int t = 8; t < 16; ++t) {
        floatx4 acc = {0.f, 0.f, 0.f, 0.f};
#pragma unroll
        for (int d = -3; d <= 3; ++d) {
            int tp = t + d;                 // clipped to [5,15]
            if (tp <= 15) acc += kw[d + 3] * w[tp - 5];
        }
        *(floatx4*)(ob + (size_t)t * ts) = acc;
    }
}

extern "C" void kernel_launch(void* const* d_in, const int* in_sizes, int n_in,
                              void* d_out, int out_size, void* d_ws, size_t ws_size,
                              hipStream_t stream) {
    const float* x   = (const float*)d_in[0];
    const float* W1  = (const float*)d_in[1];
    const float* W2  = (const float*)d_in[2];
    const float* Wl1 = (const float*)d_in[3];
    const float* Wl2 = (const float*)d_in[4];
    float* out = (float*)d_out;

    float* pooled = (float*)d_ws;              // B*C*T   = 32768 floats
    float* ty     = pooled + B_ * C_ * T_;     // B*CO*T  =  8192 floats

    pool_kernel<<<B_ * T_ * 4, 256, 0, stream>>>(x, pooled);
    ty_kernel<<<B_ * CO_, 256, 0, stream>>>(pooled, Wl1, ty);
    stream_coef_kernel<<<B_ * C_, 256, 0, stream>>>(x, pooled, ty, W1, W2, Wl2, out);
}

// Round 12
// 66.761 us; speedup vs baseline: 2.4199x; 1.0033x over previous
//
#include <hip/hip_runtime.h>

// Problem constants (from reference setup_inputs)
constexpr int B_  = 8;
constexpr int T_  = 16;
constexpr int C_  = 256;
constexpr int HW_ = 784;   // 28*28
constexpr int CO_ = 64;    // C/4
constexpr int K_  = 7;     // KSZ
constexpr int U2_ = 32;    // 2*T

typedef float floatx4 __attribute__((ext_vector_type(4)));

__device__ __forceinline__ float rfl(float v) {
    return __int_as_float(__builtin_amdgcn_readfirstlane(__float_as_int(v)));
}

// ---------------------------------------------------------------------------
// Kernel 1: pool v3 — TLP x ILP. Block = (b, t, 16-channel group).
// 2048 blocks (8/CU), 256 threads = 16 channels x 16 lanes; each lane reads
// <=13 float4s of its channel (13 independent loads in flight, ~52 VGPRs),
// then a 4-shuffle reduce over the 16 lanes of each channel.
// Wave footprint per step: 4 channels x 256B contiguous segments.
// ---------------------------------------------------------------------------
__global__ __launch_bounds__(256) void pool_kernel(const float* __restrict__ x,
                                                   float* __restrict__ pooled) {
    int bid = blockIdx.x;            // (b*T + t)*16 + cg
    int cg  = bid & 15;
    int bt  = bid >> 4;              // b*T + t
    int t   = bt & 15;
    int b   = bt >> 4;
    int tid = threadIdx.x;
    int ci  = tid >> 4;              // channel within group (0..15)
    int j16 = tid & 15;              // lane within channel
    int c   = cg * 16 + ci;

    const floatx4* p4 = (const floatx4*)(x + ((size_t)bt * C_ + c) * HW_);

    float s = 0.f;
#pragma unroll
    for (int jj = 0; jj < 13; ++jj) {
        int idx = j16 + 16 * jj;
        if (idx < 196) {
            floatx4 v = p4[idx];
            s += (v.x + v.y) + (v.z + v.w);
        }
    }
    // reduce over the 16 lanes of this channel (lanes ci*16 .. ci*16+15)
    s += __shfl_xor(s, 1, 64);
    s += __shfl_xor(s, 2, 64);
    s += __shfl_xor(s, 4, 64);
    s += __shfl_xor(s, 8, 64);
    if (j16 == 0) pooled[((size_t)b * C_ + c) * T_ + t] = s * (1.0f / 784.0f);
}

// ---------------------------------------------------------------------------
// Kernel 2: L-branch conv1d (C -> C/4, k=7, pad=3) + tanh
// ---------------------------------------------------------------------------
__global__ __launch_bounds__(256) void ty_kernel(const float* __restrict__ pooled,
                                                 const float* __restrict__ Wl1,
                                                 float* __restrict__ ty) {
    int b = blockIdx.x / CO_;
    int o = blockIdx.x % CO_;
    __shared__ float pld[T_ * 257];   // pld[t*257 + i], padded pitch

    int tid = threadIdx.x;
    for (int idx = tid; idx < C_ * T_; idx += 256) {
        int i  = idx >> 4;
        int tt = idx & 15;
        pld[tt * 257 + i] = pooled[((size_t)b * C_ + i) * T_ + tt];
    }
    __syncthreads();

    int t = tid >> 4;   // 0..15
    int q = tid & 15;   // i-split
    const float* wrow = Wl1 + (size_t)o * (C_ * K_);
    float acc = 0.f;
    for (int j = 0; j < 16; ++j) {
        int i = j * 16 + q;
        const float* wp = wrow + i * K_;
#pragma unroll
        for (int k = 0; k < K_; ++k) {
            int tt = t + k - 3;
            if (tt >= 0 && tt < T_) acc += wp[k] * pld[tt * 257 + i];
        }
    }
    acc += __shfl_xor(acc, 1, 64);
    acc += __shfl_xor(acc, 2, 64);
    acc += __shfl_xor(acc, 4, 64);
    acc += __shfl_xor(acc, 8, 64);
    if (q == 0) ty[((size_t)b * CO_ + o) * T_ + t] = tanhf(acc);
}

// ---------------------------------------------------------------------------
// Kernel 3: fused coefficients + stream (identical to R11).
// ---------------------------------------------------------------------------
__global__ __launch_bounds__(256) void stream_coef_kernel(const float* __restrict__ x,
                                                          const float* __restrict__ pooled,
                                                          const float* __restrict__ ty,
                                                          const float* __restrict__ W1,
                                                          const float* __restrict__ W2,
                                                          const float* __restrict__ Wl2,
                                                          float* __restrict__ out) {
    int bc = blockIdx.x;         // block-uniform
    int b  = bc >> 8;
    int c  = bc & 255;
    int tid = threadIdx.x;
    bool active = tid < 196;

    const size_t chan = ((size_t)(b * T_) * C_ + c) * HW_ + (size_t)tid * 4;
    const float* xb = x + chan;
    float*       ob = out + chan;
    const size_t ts = (size_t)C_ * HW_;   // t-stride in floats

    // ---- Phase A: prefetch first 11 x tiles (raw, loc applied later)
    floatx4 w[11];
    if (active) {
#pragma unroll
        for (int tp = 0; tp < 11; ++tp)
            w[tp] = *(const floatx4*)(xb + (size_t)tp * ts);
    }

    // ---- Phase B: coefficients (all 256 threads; loads overlap Phase A)
    __shared__ float loc_s[T_];
    __shared__ float g_s[U2_];
    __shared__ float s_s[8];
    __shared__ float kw_s[8];

    {   // loc: 16 t-groups x 16 o-splitters (4 o each)
        int t = tid >> 4, q = tid & 15;
        float acc = 0.f;
#pragma unroll
        for (int jj = 0; jj < 4; ++jj) {
            int o = q + jj * 16;
            acc += Wl2[(size_t)c * CO_ + o] * ty[((size_t)b * CO_ + o) * T_ + t];
        }
        acc += __shfl_xor(acc, 1, 64);
        acc += __shfl_xor(acc, 2, 64);
        acc += __shfl_xor(acc, 4, 64);
        acc += __shfl_xor(acc, 8, 64);
        if (q == 0) loc_s[t] = 1.0f / (1.0f + __expf(-acc));
    }
    if (tid < U2_) {
        float acc = 0.f;
#pragma unroll
        for (int t2 = 0; t2 < T_; ++t2)
            acc += pooled[(size_t)bc * T_ + t2] * W1[tid * T_ + t2];
        g_s[tid] = tanhf(acc);
    }
    __syncthreads();
    if (tid < K_) {
        float acc = 0.f;
#pragma unroll
        for (int u = 0; u < U2_; ++u) acc += g_s[u] * W2[tid * U2_ + u];
        s_s[tid] = acc;
    }
    __syncthreads();
    if (tid == 0) {
        float m = s_s[0];
#pragma unroll
        for (int k = 1; k < K_; ++k) m = fmaxf(m, s_s[k]);
        float e[K_], sum = 0.f;
#pragma unroll
        for (int k = 0; k < K_; ++k) { e[k] = __expf(s_s[k] - m); sum += e[k]; }
        float inv = 1.0f / sum;
#pragma unroll
        for (int k = 0; k < K_; ++k) kw_s[k] = e[k] * inv;
    }
    __syncthreads();

    // uniform coefficients -> SGPR
    float kw[K_], lc[T_];
#pragma unroll
    for (int k = 0; k < K_; ++k) kw[k] = rfl(kw_s[k]);
#pragma unroll
    for (int t = 0; t < T_; ++t) lc[t] = rfl(loc_s[t]);

    if (!active) return;

    // ---- Phase C: gate, conv, store
#pragma unroll
    for (int tp = 0; tp < 11; ++tp) w[tp] *= lc[tp];

#pragma unroll
    for (int t = 0; t < 8; ++t) {
        floatx4 acc = {0.f, 0.f, 0.f, 0.f};
#pragma unroll
        for (int d = -3; d <= 3; ++d) {
            int tp = t + d;
            if (tp >= 0 && tp <= 10) acc += kw[d + 3] * w[tp];
        }
        *(floatx4*)(ob + (size_t)t * ts) = acc;
    }

    // shift window: w[0..5] = y[5..10]; load y[11..15] into w[6..10]
#pragma unroll
    for (int j = 0; j < 6; ++j) w[j] = w[5 + j];
#pragma unroll
    for (int tp = 11; tp < 16; ++tp)
        w[tp - 5] = *(const floatx4*)(xb + (size_t)tp * ts) * lc[tp];

#pragma unroll
    for (int t = 8; t < 16; ++t) {
        floatx4 acc = {0.f, 0.f, 0.f, 0.f};
#pragma unroll
        for (int d = -3; d <= 3; ++d) {
            int tp = t + d;                 // clipped to [5,15]
            if (tp <= 15) acc += kw[d + 3] * w[tp - 5];
        }
        *(floatx4*)(ob + (size_t)t * ts) = acc;
    }
}

extern "C" void kernel_launch(void* const* d_in, const int* in_sizes, int n_in,
                              void* d_out, int out_size, void* d_ws, size_t ws_size,
                              hipStream_t stream) {
    const float* x   = (const float*)d_in[0];
    const float* W1  = (const float*)d_in[1];
    const float* W2  = (const float*)d_in[2];
    const float* Wl1 = (const float*)d_in[3];
    const float* Wl2 = (const float*)d_in[4];
    float* out = (float*)d_out;

    float* pooled = (float*)d_ws;              // B*C*T   = 32768 floats
    float* ty     = pooled + B_ * C_ * T_;     // B*CO*T  =  8192 floats

    pool_kernel<<<B_ * T_ * 16, 256, 0, stream>>>(x, pooled);
    ty_kernel<<<B_ * CO_, 256, 0, stream>>>(pooled, Wl1, ty);
    stream_coef_kernel<<<B_ * C_, 256, 0, stream>>>(x, pooled, ty, W1, W2, Wl2, out);
}